// Round 1
// baseline (706.024 us; speedup 1.0000x reference)
//
#include <hip/hip_runtime.h>
#include <hip/hip_bf16.h>
#include <math.h>

#define NN 50000
#define NE 625000
#define NG 256
#define CH 128
#define NPAD 50048

// ---------------- CSR build ----------------

__global__ __launch_bounds__(256) void k_hist(const int* __restrict__ dst, int* __restrict__ counts, int n) {
    int e = blockIdx.x * 256 + threadIdx.x;
    if (e < n) atomicAdd(&counts[dst[e]], 1);
}

__global__ __launch_bounds__(256) void k_scan1(const int* __restrict__ counts, int* __restrict__ partial, int n) {
    __shared__ int s[256];
    int t = threadIdx.x;
    int i = blockIdx.x * 256 + t;
    s[t] = (i < n) ? counts[i] : 0;
    __syncthreads();
    for (int d = 128; d > 0; d >>= 1) {
        if (t < d) s[t] += s[t + d];
        __syncthreads();
    }
    if (t == 0) partial[blockIdx.x] = s[0];
}

__global__ __launch_bounds__(256) void k_scan2(const int* __restrict__ partial, int* __restrict__ blockoff, int nb) {
    __shared__ int s[256];
    int t = threadIdx.x;
    int v = (t < nb) ? partial[t] : 0;
    s[t] = v;
    __syncthreads();
    for (int d = 1; d < 256; d <<= 1) {
        int x = (t >= d) ? s[t - d] : 0;
        __syncthreads();
        s[t] += x;
        __syncthreads();
    }
    if (t < nb) blockoff[t] = s[t] - v;  // exclusive
}

__global__ __launch_bounds__(256) void k_scan3(const int* __restrict__ counts, const int* __restrict__ blockoff,
                                               int* __restrict__ offsets, int n) {
    __shared__ int s[256];
    int t = threadIdx.x;
    int i = blockIdx.x * 256 + t;
    int v = (i < n) ? counts[i] : 0;
    s[t] = v;
    __syncthreads();
    for (int d = 1; d < 256; d <<= 1) {
        int x = (t >= d) ? s[t - d] : 0;
        __syncthreads();
        s[t] += x;
        __syncthreads();
    }
    if (i < n) offsets[i] = s[t] - v + blockoff[blockIdx.x];
}

__global__ __launch_bounds__(256) void k_fill(const int* __restrict__ src, const int* __restrict__ dst,
                                              const int* __restrict__ offsets, int* __restrict__ cursor,
                                              int* __restrict__ srclist, int n) {
    int e = blockIdx.x * 256 + threadIdx.x;
    if (e < n) {
        int d = dst[e];
        int pos = atomicAdd(&cursor[d], 1);
        srclist[offsets[d] + pos] = src[e];
    }
}

// ---------------- aggregation: out[n] = h[n] + sum_{e: dst=n} h[src(e)] ----------------

__global__ __launch_bounds__(128) void k_gather(const float* __restrict__ h, const int* __restrict__ srclist,
                                                const int* __restrict__ offsets, const int* __restrict__ counts,
                                                float* __restrict__ outb) {
    int node = blockIdx.x;
    int c = threadIdx.x;
    int off = offsets[node];
    int deg = counts[node];
    float acc = h[node * CH + c];
    for (int i = 0; i < deg; i++) {
        int s2 = srclist[off + i];
        acc += h[s2 * CH + c];
    }
    outb[node * CH + c] = acc;
}

// ---------------- dense 128->128 (+bias, optional relu) ----------------
// 64 rows x 128 cols per block; 256 threads as 16x16; micro-tile 4 rows x 8 cols.

__global__ __launch_bounds__(256) void k_dense(const float* __restrict__ A, const float* __restrict__ W,
                                               const float* __restrict__ bias, float* __restrict__ out,
                                               int nrows, int dorelu) {
    __shared__ float As[32][68];    // [k][row], padded to kill bank conflicts
    __shared__ float Ws[32][128];   // [k][col]
    int t = threadIdx.x;
    int tx = t & 15;   // col group: 8 cols each
    int ty = t >> 4;   // row group: 4 rows each
    int rowBase = blockIdx.x * 64;

    float acc[4][8];
#pragma unroll
    for (int i = 0; i < 4; i++)
#pragma unroll
        for (int j = 0; j < 8; j++) acc[i][j] = 0.f;

    for (int kt = 0; kt < 4; kt++) {
        // stage A tile (64 rows x 32 k), transposed into As[k][row]
#pragma unroll
        for (int j = 0; j < 2; j++) {
            int fid = t + j * 256;          // 0..511
            int row = fid >> 3;             // 0..63
            int kq = fid & 7;               // k-quad
            int r = rowBase + row;
            if (r >= nrows) r = nrows - 1;  // clamp (stores are guarded)
            float4 av = *(const float4*)&A[r * CH + kt * 32 + kq * 4];
            As[kq * 4 + 0][row] = av.x;
            As[kq * 4 + 1][row] = av.y;
            As[kq * 4 + 2][row] = av.z;
            As[kq * 4 + 3][row] = av.w;
        }
        // stage W tile (32 k x 128 cols)
#pragma unroll
        for (int j = 0; j < 4; j++) {
            int fid = t + j * 256;          // 0..1023
            int k = fid >> 5;               // 0..31
            int cq = fid & 31;              // col-quad
            *(float4*)&Ws[k][cq * 4] = *(const float4*)&W[(kt * 32 + k) * CH + cq * 4];
        }
        __syncthreads();
#pragma unroll
        for (int k = 0; k < 32; k++) {
            float4 a = *(const float4*)&As[k][ty * 4];
            float4 w0 = *(const float4*)&Ws[k][tx * 8];
            float4 w1 = *(const float4*)&Ws[k][tx * 8 + 4];
            float av[4] = {a.x, a.y, a.z, a.w};
            float wv[8] = {w0.x, w0.y, w0.z, w0.w, w1.x, w1.y, w1.z, w1.w};
#pragma unroll
            for (int i = 0; i < 4; i++)
#pragma unroll
                for (int j = 0; j < 8; j++) acc[i][j] += av[i] * wv[j];
        }
        __syncthreads();
    }

    float4 b0 = *(const float4*)&bias[tx * 8];
    float4 b1 = *(const float4*)&bias[tx * 8 + 4];
    float bv[8] = {b0.x, b0.y, b0.z, b0.w, b1.x, b1.y, b1.z, b1.w};
#pragma unroll
    for (int i = 0; i < 4; i++) {
        int r = rowBase + ty * 4 + i;
        if (r < nrows) {
            float o[8];
#pragma unroll
            for (int j = 0; j < 8; j++) {
                float v = acc[i][j] + bv[j];
                o[j] = dorelu ? (v > 0.f ? v : 0.f) : v;
            }
            *(float4*)&out[r * CH + tx * 8] = make_float4(o[0], o[1], o[2], o[3]);
            *(float4*)&out[r * CH + tx * 8 + 4] = make_float4(o[4], o[5], o[6], o[7]);
        }
    }
}

// ---------------- pooling (graph_id sorted -> binary search ranges) ----------------

__device__ int lowerb(const int* a, int n, int key) {
    int lo = 0, hi = n;
    while (lo < hi) {
        int mid = (lo + hi) >> 1;
        if (a[mid] < key) lo = mid + 1;
        else hi = mid;
    }
    return lo;
}

__global__ __launch_bounds__(128) void k_pool(const float* __restrict__ h, const int* __restrict__ gid,
                                              float* __restrict__ pooled) {
    __shared__ int bounds[2];
    int g = blockIdx.x;
    int c = threadIdx.x;
    if (c == 0) {
        bounds[0] = lowerb(gid, NN, g);
        bounds[1] = lowerb(gid, NN, g + 1);
    }
    __syncthreads();
    int lo = bounds[0], hi = bounds[1];
    float acc = 0.f;
    for (int n2 = lo; n2 < hi; n2++) acc += h[n2 * CH + c];
    float cnt = (float)(hi - lo);
    if (cnt < 1.f) cnt = 1.f;
    pooled[g * CH + c] = acc / cnt;
}

// ---------------- head: relu(pooled@W1+b1) @ W2 + b2 -> softmax ----------------

__global__ __launch_bounds__(128) void k_head(const float* __restrict__ pooled, const float* __restrict__ W1,
                                              const float* __restrict__ b1, const float* __restrict__ W2,
                                              const float* __restrict__ b2, float* __restrict__ out) {
    __shared__ float p[CH];
    __shared__ float h1[CH];
    __shared__ float lg[10];
    int b = blockIdx.x;
    int c = threadIdx.x;
    p[c] = pooled[b * CH + c];
    __syncthreads();
    float acc = b1[c];
    for (int k = 0; k < CH; k++) acc += p[k] * W1[k * CH + c];
    h1[c] = acc > 0.f ? acc : 0.f;
    __syncthreads();
    if (c < 10) {
        float a = b2[c];
        for (int k = 0; k < CH; k++) a += h1[k] * W2[k * 10 + c];
        lg[c] = a;
    }
    __syncthreads();
    if (c == 0) {
        float m = lg[0];
        for (int o = 1; o < 10; o++) m = fmaxf(m, lg[o]);
        float e[10];
        float s = 0.f;
        for (int o = 0; o < 10; o++) {
            e[o] = expf(lg[o] - m);
            s += e[o];
        }
        for (int o = 0; o < 10; o++) out[b * 10 + o] = e[o] / s;
    }
}

// ---------------- launch ----------------

extern "C" void kernel_launch(void* const* d_in, const int* in_sizes, int n_in,
                              void* d_out, int out_size, void* d_ws, size_t ws_size,
                              hipStream_t stream) {
    const float* x    = (const float*)d_in[0];
    const int* esrc   = (const int*)d_in[1];
    const int* edst   = (const int*)d_in[2];
    const int* gid    = (const int*)d_in[3];
    const float* convW = (const float*)d_in[4];
    const float* convb = (const float*)d_in[5];
    const float* d1W  = (const float*)d_in[6];
    const float* d1b  = (const float*)d_in[7];
    const float* d2W  = (const float*)d_in[8];
    const float* d2b  = (const float*)d_in[9];
    float* out = (float*)d_out;

    char* ws = (char*)d_ws;
    size_t off = 0;
    auto alloc = [&](size_t bytes) -> void* {
        void* p = ws + off;
        off += (bytes + 255) & ~(size_t)255;
        return p;
    };
    float* bufA   = (float*)alloc((size_t)NPAD * CH * 4);
    float* bufB   = (float*)alloc((size_t)NPAD * CH * 4);
    int* counts   = (int*)alloc((size_t)NN * 4);
    int* offs     = (int*)alloc((size_t)NN * 4);
    int* cursor   = (int*)alloc((size_t)NN * 4);
    int* srclist  = (int*)alloc((size_t)NE * 4);
    int* partial  = (int*)alloc(256 * 4);
    int* blockoff = (int*)alloc(256 * 4);
    float* pooled = (float*)alloc((size_t)NG * CH * 4);

    hipMemsetAsync(counts, 0, (size_t)NN * 4, stream);
    hipMemsetAsync(cursor, 0, (size_t)NN * 4, stream);

    k_hist<<<(NE + 255) / 256, 256, 0, stream>>>(edst, counts, NE);
    int nb = (NN + 255) / 256;  // 196
    k_scan1<<<nb, 256, 0, stream>>>(counts, partial, NN);
    k_scan2<<<1, 256, 0, stream>>>(partial, blockoff, nb);
    k_scan3<<<nb, 256, 0, stream>>>(counts, blockoff, offs, NN);
    k_fill<<<(NE + 255) / 256, 256, 0, stream>>>(esrc, edst, offs, cursor, srclist, NE);

    const float* hcur = x;
    int nblk = (NN + 63) / 64;
    for (int l = 0; l < 3; l++) {
        k_gather<<<NN, 128, 0, stream>>>(hcur, srclist, offs, counts, bufB);
        k_dense<<<nblk, 256, 0, stream>>>(bufB, convW + (size_t)(l * 3 + 0) * CH * CH, convb + (l * 3 + 0) * CH, bufA, NN, 1);
        k_dense<<<nblk, 256, 0, stream>>>(bufA, convW + (size_t)(l * 3 + 1) * CH * CH, convb + (l * 3 + 1) * CH, bufB, NN, 1);
        k_dense<<<nblk, 256, 0, stream>>>(bufB, convW + (size_t)(l * 3 + 2) * CH * CH, convb + (l * 3 + 2) * CH, bufA, NN, 0);
        hcur = bufA;
    }
    k_pool<<<NG, 128, 0, stream>>>(bufA, gid, pooled);
    k_head<<<NG, 128, 0, stream>>>(pooled, d1W, d1b, d2W, d2b, out);
}

// Round 2
// 457.459 us; speedup vs baseline: 1.5434x; 1.5434x over previous
//
#include <hip/hip_runtime.h>
#include <hip/hip_bf16.h>
#include <math.h>

#define NN 50000
#define NE 625000
#define NG 256
#define CH 128
#define NPAD 50048
#define PADK 136  // 128 + 8 bf16 pad -> 272B row stride (16B-aligned, bank-conflict-free frag reads)

typedef __attribute__((ext_vector_type(8))) short short8;
typedef __attribute__((ext_vector_type(4))) float floatx4;

__device__ __forceinline__ float bf2f_lo(unsigned u) {
    union { unsigned i; float f; } c; c.i = u << 16; return c.f;
}
__device__ __forceinline__ float bf2f_hi(unsigned u) {
    union { unsigned i; float f; } c; c.i = u & 0xffff0000u; return c.f;
}
__device__ __forceinline__ unsigned short f2bfu(float f) {
    __hip_bfloat16 b = __float2bfloat16(f);
    union { __hip_bfloat16 b; unsigned short u; } c; c.b = b; return c.u;
}

// ---------------- CSR build ----------------

__global__ __launch_bounds__(256) void k_hist(const int* __restrict__ dst, int* __restrict__ counts, int n) {
    int e = blockIdx.x * 256 + threadIdx.x;
    if (e < n) atomicAdd(&counts[dst[e]], 1);
}

__global__ __launch_bounds__(256) void k_scan1(const int* __restrict__ counts, int* __restrict__ partial, int n) {
    __shared__ int s[256];
    int t = threadIdx.x;
    int i = blockIdx.x * 256 + t;
    s[t] = (i < n) ? counts[i] : 0;
    __syncthreads();
    for (int d = 128; d > 0; d >>= 1) {
        if (t < d) s[t] += s[t + d];
        __syncthreads();
    }
    if (t == 0) partial[blockIdx.x] = s[0];
}

__global__ __launch_bounds__(256) void k_scan2(const int* __restrict__ partial, int* __restrict__ blockoff, int nb) {
    __shared__ int s[256];
    int t = threadIdx.x;
    int v = (t < nb) ? partial[t] : 0;
    s[t] = v;
    __syncthreads();
    for (int d = 1; d < 256; d <<= 1) {
        int x = (t >= d) ? s[t - d] : 0;
        __syncthreads();
        s[t] += x;
        __syncthreads();
    }
    if (t < nb) blockoff[t] = s[t] - v;  // exclusive
}

__global__ __launch_bounds__(256) void k_scan3(const int* __restrict__ counts, const int* __restrict__ blockoff,
                                               int* __restrict__ offsets, int n) {
    __shared__ int s[256];
    int t = threadIdx.x;
    int i = blockIdx.x * 256 + t;
    int v = (i < n) ? counts[i] : 0;
    s[t] = v;
    __syncthreads();
    for (int d = 1; d < 256; d <<= 1) {
        int x = (t >= d) ? s[t - d] : 0;
        __syncthreads();
        s[t] += x;
        __syncthreads();
    }
    if (i < n) offsets[i] = s[t] - v + blockoff[blockIdx.x];
}

__global__ __launch_bounds__(256) void k_fill(const int* __restrict__ src, const int* __restrict__ dst,
                                              const int* __restrict__ offsets, int* __restrict__ cursor,
                                              int* __restrict__ srclist, int n) {
    int e = blockIdx.x * 256 + threadIdx.x;
    if (e < n) {
        int d = dst[e];
        int pos = atomicAdd(&cursor[d], 1);
        srclist[offsets[d] + pos] = src[e];
    }
}

// ---------------- prep: fp32 -> bf16 conversions ----------------

__global__ __launch_bounds__(256) void k_prep_x(const float* __restrict__ x, unsigned short* __restrict__ hb, int n4) {
    int i = blockIdx.x * 256 + threadIdx.x;
    if (i < n4) {
        float4 v = *(const float4*)&x[i * 4];
        ushort4 o;
        o.x = f2bfu(v.x); o.y = f2bfu(v.y); o.z = f2bfu(v.z); o.w = f2bfu(v.w);
        *(ushort4*)&hb[i * 4] = o;
    }
}

// transpose+convert 9 conv weight mats: Wt[mat][n][k] = W[mat][k][n]
__global__ __launch_bounds__(256) void k_prep_w(const float* __restrict__ W, unsigned short* __restrict__ Wt, int total) {
    int i = blockIdx.x * 256 + threadIdx.x;
    if (i < total) {
        int mat = i >> 14;
        int rem = i & 16383;
        int k = rem >> 7;
        int n = rem & 127;
        Wt[mat * 16384 + n * 128 + k] = f2bfu(W[i]);
    }
}

// ---------------- aggregation (bf16): out[n] = h[n] + sum_{e: dst=n} h[src(e)] ----------------
// 16 lanes per node (ushort8 = 8 channels/lane), 16 nodes per 256-thread block.

__global__ __launch_bounds__(256) void k_gather(const unsigned short* __restrict__ h, const int* __restrict__ srclist,
                                                const int* __restrict__ offsets, const int* __restrict__ counts,
                                                unsigned short* __restrict__ outb) {
    int t = threadIdx.x;
    int node = blockIdx.x * 16 + (t >> 4);
    int sub = t & 15;
    int off = offsets[node];
    int deg = counts[node];

    float acc[8];
    {
        uint4 v = *(const uint4*)&h[(size_t)node * CH + sub * 8];
        acc[0] = bf2f_lo(v.x); acc[1] = bf2f_hi(v.x);
        acc[2] = bf2f_lo(v.y); acc[3] = bf2f_hi(v.y);
        acc[4] = bf2f_lo(v.z); acc[5] = bf2f_hi(v.z);
        acc[6] = bf2f_lo(v.w); acc[7] = bf2f_hi(v.w);
    }
    int i = 0;
    for (; i + 1 < deg; i += 2) {
        int s0 = srclist[off + i];
        int s1 = srclist[off + i + 1];
        uint4 v0 = *(const uint4*)&h[(size_t)s0 * CH + sub * 8];
        uint4 v1 = *(const uint4*)&h[(size_t)s1 * CH + sub * 8];
        acc[0] += bf2f_lo(v0.x); acc[1] += bf2f_hi(v0.x);
        acc[2] += bf2f_lo(v0.y); acc[3] += bf2f_hi(v0.y);
        acc[4] += bf2f_lo(v0.z); acc[5] += bf2f_hi(v0.z);
        acc[6] += bf2f_lo(v0.w); acc[7] += bf2f_hi(v0.w);
        acc[0] += bf2f_lo(v1.x); acc[1] += bf2f_hi(v1.x);
        acc[2] += bf2f_lo(v1.y); acc[3] += bf2f_hi(v1.y);
        acc[4] += bf2f_lo(v1.z); acc[5] += bf2f_hi(v1.z);
        acc[6] += bf2f_lo(v1.w); acc[7] += bf2f_hi(v1.w);
    }
    if (i < deg) {
        int s0 = srclist[off + i];
        uint4 v0 = *(const uint4*)&h[(size_t)s0 * CH + sub * 8];
        acc[0] += bf2f_lo(v0.x); acc[1] += bf2f_hi(v0.x);
        acc[2] += bf2f_lo(v0.y); acc[3] += bf2f_hi(v0.y);
        acc[4] += bf2f_lo(v0.z); acc[5] += bf2f_hi(v0.z);
        acc[6] += bf2f_lo(v0.w); acc[7] += bf2f_hi(v0.w);
    }
    ushort4 o0, o1;
    o0.x = f2bfu(acc[0]); o0.y = f2bfu(acc[1]); o0.z = f2bfu(acc[2]); o0.w = f2bfu(acc[3]);
    o1.x = f2bfu(acc[4]); o1.y = f2bfu(acc[5]); o1.z = f2bfu(acc[6]); o1.w = f2bfu(acc[7]);
    *(ushort4*)&outb[(size_t)node * CH + sub * 8] = o0;
    *(ushort4*)&outb[(size_t)node * CH + sub * 8 + 4] = o1;
}

// ---------------- dense 128->128 bf16 MFMA ----------------
// Block 128 rows x 128 cols, 256 threads = 4 waves in 2x2 (M x N) arrangement.
// Wave tile 64x64 = 4x4 MFMA tiles of 16x16x32. W b-frags live in registers
// (loaded from pre-transposed bf16 Wt, L2-hot). A staged once in LDS (K=128
// entirely resident -> single barrier, no K-staging loop).

__global__ __launch_bounds__(256) void k_dense(const unsigned short* __restrict__ A, const unsigned short* __restrict__ Wt,
                                               const float* __restrict__ bias, void* __restrict__ outp,
                                               int nrows, int dorelu, int outFp32) {
    __shared__ unsigned short As[128 * PADK];  // 34.8 KB

    int t = threadIdx.x;
    int wave = t >> 6;
    int lane = t & 63;
    int q = lane >> 4;     // k-quad
    int ml = lane & 15;    // row/col within 16-tile
    int waveM = (wave >> 1) * 64;
    int waveN = (wave & 1) * 64;
    int rowBase = blockIdx.x * 128;

    // W b-frags in registers: b[nt][s] = Wt[waveN+nt*16+ml][s*32+q*8 .. +7]
    short8 b[4][4];
#pragma unroll
    for (int nt = 0; nt < 4; nt++) {
        int n = waveN + nt * 16 + ml;
#pragma unroll
        for (int s = 0; s < 4; s++) {
            b[nt][s] = *(const short8*)&Wt[n * 128 + s * 32 + q * 8];
        }
    }

    // stage A tile: 128 rows x 16 chunks of 8 bf16 (16B). Global: 4 rows = 1KB
    // contiguous per wave. LDS: within quarter-wave banks stride 4 -> 2-way free.
#pragma unroll
    for (int iter = 0; iter < 8; iter++) {
        int fid = t + iter * 256;
        int row = fid >> 4;
        int ch = fid & 15;
        int r = rowBase + row;
        if (r >= nrows) r = nrows - 1;
        uint4 v = *(const uint4*)&A[(size_t)r * CH + ch * 8];
        *(uint4*)&As[row * PADK + ch * 8] = v;
    }
    __syncthreads();

    floatx4 acc[4][4];
#pragma unroll
    for (int mt = 0; mt < 4; mt++)
#pragma unroll
        for (int nt = 0; nt < 4; nt++) acc[mt][nt] = (floatx4){0.f, 0.f, 0.f, 0.f};

#pragma unroll
    for (int s = 0; s < 4; s++) {
        short8 a[4];
#pragma unroll
        for (int mt = 0; mt < 4; mt++) {
            int m = waveM + mt * 16 + ml;
            a[mt] = *(const short8*)&As[m * PADK + s * 32 + q * 8];
        }
#pragma unroll
        for (int mt = 0; mt < 4; mt++)
#pragma unroll
            for (int nt = 0; nt < 4; nt++)
                acc[mt][nt] = __builtin_amdgcn_mfma_f32_16x16x32_bf16(a[mt], b[nt][s], acc[mt][nt], 0, 0, 0);
    }

    // epilogue: bias + optional relu; C[row][col]: col=lane&15, row=q*4+reg
    float bv[4];
#pragma unroll
    for (int nt = 0; nt < 4; nt++) bv[nt] = bias[waveN + nt * 16 + ml];

    float* outF = (float*)outp;
    unsigned short* outB = (unsigned short*)outp;
#pragma unroll
    for (int mt = 0; mt < 4; mt++) {
#pragma unroll
        for (int reg = 0; reg < 4; reg++) {
            int r = rowBase + waveM + mt * 16 + q * 4 + reg;
            if (r < nrows) {
#pragma unroll
                for (int nt = 0; nt < 4; nt++) {
                    int col = waveN + nt * 16 + ml;
                    float v = acc[mt][nt][reg] + bv[nt];
                    if (dorelu) v = v > 0.f ? v : 0.f;
                    if (outFp32) outF[(size_t)r * CH + col] = v;
                    else outB[(size_t)r * CH + col] = f2bfu(v);
                }
            }
        }
    }
}

// ---------------- pooling (graph_id sorted -> binary search ranges) ----------------

__device__ int lowerb(const int* a, int n, int key) {
    int lo = 0, hi = n;
    while (lo < hi) {
        int mid = (lo + hi) >> 1;
        if (a[mid] < key) lo = mid + 1;
        else hi = mid;
    }
    return lo;
}

__global__ __launch_bounds__(128) void k_pool(const float* __restrict__ h, const int* __restrict__ gid,
                                              float* __restrict__ pooled) {
    __shared__ int bounds[2];
    int g = blockIdx.x;
    int c = threadIdx.x;
    if (c == 0) {
        bounds[0] = lowerb(gid, NN, g);
        bounds[1] = lowerb(gid, NN, g + 1);
    }
    __syncthreads();
    int lo = bounds[0], hi = bounds[1];
    float acc = 0.f;
    for (int n2 = lo; n2 < hi; n2++) acc += h[(size_t)n2 * CH + c];
    float cnt = (float)(hi - lo);
    if (cnt < 1.f) cnt = 1.f;
    pooled[g * CH + c] = acc / cnt;
}

// ---------------- head: relu(pooled@W1+b1) @ W2 + b2 -> softmax ----------------

__global__ __launch_bounds__(128) void k_head(const float* __restrict__ pooled, const float* __restrict__ W1,
                                              const float* __restrict__ b1, const float* __restrict__ W2,
                                              const float* __restrict__ b2, float* __restrict__ out) {
    __shared__ float p[CH];
    __shared__ float h1[CH];
    __shared__ float lg[10];
    int b = blockIdx.x;
    int c = threadIdx.x;
    p[c] = pooled[b * CH + c];
    __syncthreads();
    float acc = b1[c];
    for (int k = 0; k < CH; k++) acc += p[k] * W1[k * CH + c];
    h1[c] = acc > 0.f ? acc : 0.f;
    __syncthreads();
    if (c < 10) {
        float a = b2[c];
        for (int k = 0; k < CH; k++) a += h1[k] * W2[k * 10 + c];
        lg[c] = a;
    }
    __syncthreads();
    if (c == 0) {
        float m = lg[0];
        for (int o = 1; o < 10; o++) m = fmaxf(m, lg[o]);
        float e[10];
        float s = 0.f;
        for (int o = 0; o < 10; o++) {
            e[o] = expf(lg[o] - m);
            s += e[o];
        }
        for (int o = 0; o < 10; o++) out[b * 10 + o] = e[o] / s;
    }
}

// ---------------- launch ----------------

extern "C" void kernel_launch(void* const* d_in, const int* in_sizes, int n_in,
                              void* d_out, int out_size, void* d_ws, size_t ws_size,
                              hipStream_t stream) {
    const float* x    = (const float*)d_in[0];
    const int* esrc   = (const int*)d_in[1];
    const int* edst   = (const int*)d_in[2];
    const int* gid    = (const int*)d_in[3];
    const float* convW = (const float*)d_in[4];
    const float* convb = (const float*)d_in[5];
    const float* d1W  = (const float*)d_in[6];
    const float* d1b  = (const float*)d_in[7];
    const float* d2W  = (const float*)d_in[8];
    const float* d2b  = (const float*)d_in[9];
    float* out = (float*)d_out;

    char* ws = (char*)d_ws;
    size_t off = 0;
    auto alloc = [&](size_t bytes) -> void* {
        void* p = ws + off;
        off += (bytes + 255) & ~(size_t)255;
        return p;
    };
    // hb and tb are adjacent; the final fp32 output (bufF, NPAD*CH*4 bytes)
    // aliases [hb][tb] exactly (both dead by the final dense).
    unsigned short* hb = (unsigned short*)alloc((size_t)NPAD * CH * 2);
    unsigned short* tb = (unsigned short*)alloc((size_t)NPAD * CH * 2);
    unsigned short* gb = (unsigned short*)alloc((size_t)NPAD * CH * 2);
    float* bufF = (float*)hb;  // NPAD*CH*4 == 2 * (NPAD*CH*2), spans hb+tb

    unsigned short* Wt = (unsigned short*)alloc((size_t)9 * 128 * 128 * 2);
    int* counts   = (int*)alloc((size_t)NN * 4);
    int* offs     = (int*)alloc((size_t)NN * 4);
    int* cursor   = (int*)alloc((size_t)NN * 4);
    int* srclist  = (int*)alloc((size_t)NE * 4);
    int* partial  = (int*)alloc(256 * 4);
    int* blockoff = (int*)alloc(256 * 4);
    float* pooled = (float*)alloc((size_t)NG * CH * 4);

    hipMemsetAsync(counts, 0, (size_t)NN * 4, stream);
    hipMemsetAsync(cursor, 0, (size_t)NN * 4, stream);

    // CSR build
    k_hist<<<(NE + 255) / 256, 256, 0, stream>>>(edst, counts, NE);
    int nb = (NN + 255) / 256;  // 196
    k_scan1<<<nb, 256, 0, stream>>>(counts, partial, NN);
    k_scan2<<<1, 256, 0, stream>>>(partial, blockoff, nb);
    k_scan3<<<nb, 256, 0, stream>>>(counts, blockoff, offs, NN);
    k_fill<<<(NE + 255) / 256, 256, 0, stream>>>(esrc, edst, offs, cursor, srclist, NE);

    // prep: x -> bf16, conv weights -> bf16 transposed
    k_prep_x<<<(NN * CH / 4 + 255) / 256, 256, 0, stream>>>(x, hb, NN * CH / 4);
    k_prep_w<<<(9 * 128 * 128 + 255) / 256, 256, 0, stream>>>(convW, Wt, 9 * 128 * 128);

    int nblk = (NN + 127) / 128;  // 391
    for (int l = 0; l < 3; l++) {
        k_gather<<<NN / 16, 256, 0, stream>>>(hb, srclist, offs, counts, gb);
        k_dense<<<nblk, 256, 0, stream>>>(gb, Wt + (size_t)(l * 3 + 0) * 16384, convb + (l * 3 + 0) * CH, tb, NN, 1, 0);
        k_dense<<<nblk, 256, 0, stream>>>(tb, Wt + (size_t)(l * 3 + 1) * 16384, convb + (l * 3 + 1) * CH, gb, NN, 1, 0);
        if (l < 2) {
            k_dense<<<nblk, 256, 0, stream>>>(gb, Wt + (size_t)(l * 3 + 2) * 16384, convb + (l * 3 + 2) * CH, hb, NN, 0, 0);
        } else {
            k_dense<<<nblk, 256, 0, stream>>>(gb, Wt + (size_t)(l * 3 + 2) * 16384, convb + (l * 3 + 2) * CH, bufF, NN, 0, 1);
        }
    }
    k_pool<<<NG, 128, 0, stream>>>(bufF, gid, pooled);
    k_head<<<NG, 128, 0, stream>>>(pooled, d1W, d1b, d2W, d2b, out);
}

// Round 3
// 433.906 us; speedup vs baseline: 1.6271x; 1.0543x over previous
//
#include <hip/hip_runtime.h>
#include <hip/hip_bf16.h>
#include <math.h>

#define NN 50000
#define NE 625000
#define NG 256
#define CH 128
#define NPAD 50048
#define PADK 136  // 128 + 8 bf16 pad -> 272B row stride (16B-aligned, bank-conflict-free frag reads)

typedef __attribute__((ext_vector_type(8))) short short8;
typedef __attribute__((ext_vector_type(4))) float floatx4;

__device__ __forceinline__ float bf2f_lo(unsigned u) {
    union { unsigned i; float f; } c; c.i = u << 16; return c.f;
}
__device__ __forceinline__ float bf2f_hi(unsigned u) {
    union { unsigned i; float f; } c; c.i = u & 0xffff0000u; return c.f;
}
__device__ __forceinline__ unsigned short f2bfu(float f) {
    __hip_bfloat16 b = __float2bfloat16(f);
    union { __hip_bfloat16 b; unsigned short u; } c; c.b = b; return c.u;
}

// ---------------- CSR build ----------------

__global__ __launch_bounds__(256) void k_hist(const int* __restrict__ dst, int* __restrict__ counts, int n) {
    int e = blockIdx.x * 256 + threadIdx.x;
    if (e < n) atomicAdd(&counts[dst[e]], 1);
}

__global__ __launch_bounds__(256) void k_gcount(const int* __restrict__ gid, int* __restrict__ gcount, int n) {
    int i = blockIdx.x * 256 + threadIdx.x;
    if (i < n) atomicAdd(&gcount[gid[i]], 1);
}

__global__ __launch_bounds__(256) void k_scan1(const int* __restrict__ counts, int* __restrict__ partial, int n) {
    __shared__ int s[256];
    int t = threadIdx.x;
    int i = blockIdx.x * 256 + t;
    s[t] = (i < n) ? counts[i] : 0;
    __syncthreads();
    for (int d = 128; d > 0; d >>= 1) {
        if (t < d) s[t] += s[t + d];
        __syncthreads();
    }
    if (t == 0) partial[blockIdx.x] = s[0];
}

__global__ __launch_bounds__(256) void k_scan2(const int* __restrict__ partial, int* __restrict__ blockoff, int nb) {
    __shared__ int s[256];
    int t = threadIdx.x;
    int v = (t < nb) ? partial[t] : 0;
    s[t] = v;
    __syncthreads();
    for (int d = 1; d < 256; d <<= 1) {
        int x = (t >= d) ? s[t - d] : 0;
        __syncthreads();
        s[t] += x;
        __syncthreads();
    }
    if (t < nb) blockoff[t] = s[t] - v;  // exclusive
}

__global__ __launch_bounds__(256) void k_scan3(const int* __restrict__ counts, const int* __restrict__ blockoff,
                                               int* __restrict__ offsets, int n) {
    __shared__ int s[256];
    int t = threadIdx.x;
    int i = blockIdx.x * 256 + t;
    int v = (i < n) ? counts[i] : 0;
    s[t] = v;
    __syncthreads();
    for (int d = 1; d < 256; d <<= 1) {
        int x = (t >= d) ? s[t - d] : 0;
        __syncthreads();
        s[t] += x;
        __syncthreads();
    }
    if (i < n) offsets[i] = s[t] - v + blockoff[blockIdx.x];
}

__global__ __launch_bounds__(256) void k_fill(const int* __restrict__ src, const int* __restrict__ dst,
                                              const int* __restrict__ offsets, int* __restrict__ cursor,
                                              int* __restrict__ srclist, int n) {
    int e = blockIdx.x * 256 + threadIdx.x;
    if (e < n) {
        int d = dst[e];
        int pos = atomicAdd(&cursor[d], 1);
        srclist[offsets[d] + pos] = src[e];
    }
}

// ---------------- prep: fp32 -> bf16 conversions ----------------

__global__ __launch_bounds__(256) void k_prep_x(const float* __restrict__ x, unsigned short* __restrict__ hb, int n4) {
    int i = blockIdx.x * 256 + threadIdx.x;
    if (i < n4) {
        float4 v = *(const float4*)&x[i * 4];
        ushort4 o;
        o.x = f2bfu(v.x); o.y = f2bfu(v.y); o.z = f2bfu(v.z); o.w = f2bfu(v.w);
        *(ushort4*)&hb[i * 4] = o;
    }
}

// transpose+convert 9 conv weight mats: Wt[mat][n][k] = W[mat][k][n]
__global__ __launch_bounds__(256) void k_prep_w(const float* __restrict__ W, unsigned short* __restrict__ Wt, int total) {
    int i = blockIdx.x * 256 + threadIdx.x;
    if (i < total) {
        int mat = i >> 14;
        int rem = i & 16383;
        int k = rem >> 7;
        int n = rem & 127;
        Wt[mat * 16384 + n * 128 + k] = f2bfu(W[i]);
    }
}

// ---------------- aggregation (bf16): out[n] = h[n] + sum_{e: dst=n} h[src(e)] ----------------
// 16 lanes per node (ushort8 = 8 channels/lane), 16 nodes per 256-thread block.

__global__ __launch_bounds__(256) void k_gather(const unsigned short* __restrict__ h, const int* __restrict__ srclist,
                                                const int* __restrict__ offsets, const int* __restrict__ counts,
                                                unsigned short* __restrict__ outb) {
    int t = threadIdx.x;
    int node = blockIdx.x * 16 + (t >> 4);
    int sub = t & 15;
    int off = offsets[node];
    int deg = counts[node];

    float acc[8];
    {
        uint4 v = *(const uint4*)&h[(size_t)node * CH + sub * 8];
        acc[0] = bf2f_lo(v.x); acc[1] = bf2f_hi(v.x);
        acc[2] = bf2f_lo(v.y); acc[3] = bf2f_hi(v.y);
        acc[4] = bf2f_lo(v.z); acc[5] = bf2f_hi(v.z);
        acc[6] = bf2f_lo(v.w); acc[7] = bf2f_hi(v.w);
    }
#define ACC8(v) \
    acc[0] += bf2f_lo(v.x); acc[1] += bf2f_hi(v.x); \
    acc[2] += bf2f_lo(v.y); acc[3] += bf2f_hi(v.y); \
    acc[4] += bf2f_lo(v.z); acc[5] += bf2f_hi(v.z); \
    acc[6] += bf2f_lo(v.w); acc[7] += bf2f_hi(v.w);
    int i = 0;
    for (; i + 3 < deg; i += 4) {
        int s0 = srclist[off + i];
        int s1 = srclist[off + i + 1];
        int s2 = srclist[off + i + 2];
        int s3 = srclist[off + i + 3];
        uint4 v0 = *(const uint4*)&h[(size_t)s0 * CH + sub * 8];
        uint4 v1 = *(const uint4*)&h[(size_t)s1 * CH + sub * 8];
        uint4 v2 = *(const uint4*)&h[(size_t)s2 * CH + sub * 8];
        uint4 v3 = *(const uint4*)&h[(size_t)s3 * CH + sub * 8];
        ACC8(v0) ACC8(v1) ACC8(v2) ACC8(v3)
    }
    for (; i < deg; i++) {
        int s0 = srclist[off + i];
        uint4 v0 = *(const uint4*)&h[(size_t)s0 * CH + sub * 8];
        ACC8(v0)
    }
#undef ACC8
    ushort4 o0, o1;
    o0.x = f2bfu(acc[0]); o0.y = f2bfu(acc[1]); o0.z = f2bfu(acc[2]); o0.w = f2bfu(acc[3]);
    o1.x = f2bfu(acc[4]); o1.y = f2bfu(acc[5]); o1.z = f2bfu(acc[6]); o1.w = f2bfu(acc[7]);
    *(ushort4*)&outb[(size_t)node * CH + sub * 8] = o0;
    *(ushort4*)&outb[(size_t)node * CH + sub * 8 + 4] = o1;
}

// ---------------- dense 128->128 bf16 MFMA ----------------
// Block 128 rows x 128 cols, 256 threads = 4 waves in 2x2 (M x N) arrangement.
// Wave tile 64x64 = 4x4 MFMA tiles of 16x16x32. W b-frags live in registers
// (loaded from pre-transposed bf16 Wt, L2-hot). A staged once in LDS (K=128
// entirely resident -> single barrier, no K-staging loop).
// poolMode=1: instead of storing rows, atomicAdd (bias-added, no relu) outputs
// into pooled[gid[row]*CH + col] (fused global-avg-pool numerator).

__global__ __launch_bounds__(256) void k_dense(const unsigned short* __restrict__ A, const unsigned short* __restrict__ Wt,
                                               const float* __restrict__ bias, void* __restrict__ outp,
                                               const int* __restrict__ gidp, int nrows, int dorelu, int poolMode) {
    __shared__ unsigned short As[128 * PADK];  // 34.8 KB

    int t = threadIdx.x;
    int wave = t >> 6;
    int lane = t & 63;
    int q = lane >> 4;     // k-quad
    int ml = lane & 15;    // row/col within 16-tile
    int waveM = (wave >> 1) * 64;
    int waveN = (wave & 1) * 64;
    int rowBase = blockIdx.x * 128;

    // W b-frags in registers: b[nt][s] = Wt[waveN+nt*16+ml][s*32+q*8 .. +7]
    short8 b[4][4];
#pragma unroll
    for (int nt = 0; nt < 4; nt++) {
        int n = waveN + nt * 16 + ml;
#pragma unroll
        for (int s = 0; s < 4; s++) {
            b[nt][s] = *(const short8*)&Wt[n * 128 + s * 32 + q * 8];
        }
    }

    // stage A tile: 128 rows x 16 chunks of 8 bf16 (16B).
#pragma unroll
    for (int iter = 0; iter < 8; iter++) {
        int fid = t + iter * 256;
        int row = fid >> 4;
        int ch = fid & 15;
        int r = rowBase + row;
        if (r >= nrows) r = nrows - 1;
        uint4 v = *(const uint4*)&A[(size_t)r * CH + ch * 8];
        *(uint4*)&As[row * PADK + ch * 8] = v;
    }
    __syncthreads();

    floatx4 acc[4][4];
#pragma unroll
    for (int mt = 0; mt < 4; mt++)
#pragma unroll
        for (int nt = 0; nt < 4; nt++) acc[mt][nt] = (floatx4){0.f, 0.f, 0.f, 0.f};

#pragma unroll
    for (int s = 0; s < 4; s++) {
        short8 a[4];
#pragma unroll
        for (int mt = 0; mt < 4; mt++) {
            int m = waveM + mt * 16 + ml;
            a[mt] = *(const short8*)&As[m * PADK + s * 32 + q * 8];
        }
#pragma unroll
        for (int mt = 0; mt < 4; mt++)
#pragma unroll
            for (int nt = 0; nt < 4; nt++)
                acc[mt][nt] = __builtin_amdgcn_mfma_f32_16x16x32_bf16(a[mt], b[nt][s], acc[mt][nt], 0, 0, 0);
    }

    // epilogue: bias + optional relu; C[row][col]: col=lane&15, row=q*4+reg
    float bv[4];
#pragma unroll
    for (int nt = 0; nt < 4; nt++) bv[nt] = bias[waveN + nt * 16 + ml];

    if (!poolMode) {
        unsigned short* outB = (unsigned short*)outp;
#pragma unroll
        for (int mt = 0; mt < 4; mt++) {
#pragma unroll
            for (int reg = 0; reg < 4; reg++) {
                int r = rowBase + waveM + mt * 16 + q * 4 + reg;
                if (r < nrows) {
#pragma unroll
                    for (int nt = 0; nt < 4; nt++) {
                        int col = waveN + nt * 16 + ml;
                        float v = acc[mt][nt][reg] + bv[nt];
                        if (dorelu) v = v > 0.f ? v : 0.f;
                        outB[(size_t)r * CH + col] = f2bfu(v);
                    }
                }
            }
        }
    } else {
        float* pooled = (float*)outp;
#pragma unroll
        for (int mt = 0; mt < 4; mt++) {
            int r0 = rowBase + waveM + mt * 16 + q * 4;  // rows r0..r0+3
            if (r0 + 3 < nrows) {
                int g0 = gidp[r0];
                int g3 = gidp[r0 + 3];
                if (g0 == g3) {
                    // all 4 rows same graph (common case: sorted gid, ~195-row runs)
#pragma unroll
                    for (int nt = 0; nt < 4; nt++) {
                        int col = waveN + nt * 16 + ml;
                        float v = (acc[mt][nt][0] + acc[mt][nt][1] + acc[mt][nt][2] + acc[mt][nt][3]) + 4.f * bv[nt];
                        atomicAdd(&pooled[(size_t)g0 * CH + col], v);
                    }
                } else {
#pragma unroll
                    for (int reg = 0; reg < 4; reg++) {
                        int g = gidp[r0 + reg];
#pragma unroll
                        for (int nt = 0; nt < 4; nt++) {
                            int col = waveN + nt * 16 + ml;
                            atomicAdd(&pooled[(size_t)g * CH + col], acc[mt][nt][reg] + bv[nt]);
                        }
                    }
                }
            } else {
#pragma unroll
                for (int reg = 0; reg < 4; reg++) {
                    int r = r0 + reg;
                    if (r < nrows) {
                        int g = gidp[r];
#pragma unroll
                        for (int nt = 0; nt < 4; nt++) {
                            int col = waveN + nt * 16 + ml;
                            atomicAdd(&pooled[(size_t)g * CH + col], acc[mt][nt][reg] + bv[nt]);
                        }
                    }
                }
            }
        }
    }
}

// ---------------- head: relu((pooled/cnt)@W1+b1) @ W2 + b2 -> softmax ----------------

__global__ __launch_bounds__(128) void k_head(const float* __restrict__ pooled, const int* __restrict__ gcount,
                                              const float* __restrict__ W1, const float* __restrict__ b1,
                                              const float* __restrict__ W2, const float* __restrict__ b2,
                                              float* __restrict__ out) {
    __shared__ float p[CH];
    __shared__ float h1[CH];
    __shared__ float lg[10];
    int b = blockIdx.x;
    int c = threadIdx.x;
    float cnt = (float)gcount[b];
    if (cnt < 1.f) cnt = 1.f;
    p[c] = pooled[b * CH + c] / cnt;
    __syncthreads();
    float acc = b1[c];
    for (int k = 0; k < CH; k++) acc += p[k] * W1[k * CH + c];
    h1[c] = acc > 0.f ? acc : 0.f;
    __syncthreads();
    if (c < 10) {
        float a = b2[c];
        for (int k = 0; k < CH; k++) a += h1[k] * W2[k * 10 + c];
        lg[c] = a;
    }
    __syncthreads();
    if (c == 0) {
        float m = lg[0];
        for (int o = 1; o < 10; o++) m = fmaxf(m, lg[o]);
        float e[10];
        float s = 0.f;
        for (int o = 0; o < 10; o++) {
            e[o] = expf(lg[o] - m);
            s += e[o];
        }
        for (int o = 0; o < 10; o++) out[b * 10 + o] = e[o] / s;
    }
}

// ---------------- launch ----------------

extern "C" void kernel_launch(void* const* d_in, const int* in_sizes, int n_in,
                              void* d_out, int out_size, void* d_ws, size_t ws_size,
                              hipStream_t stream) {
    const float* x    = (const float*)d_in[0];
    const int* esrc   = (const int*)d_in[1];
    const int* edst   = (const int*)d_in[2];
    const int* gid    = (const int*)d_in[3];
    const float* convW = (const float*)d_in[4];
    const float* convb = (const float*)d_in[5];
    const float* d1W  = (const float*)d_in[6];
    const float* d1b  = (const float*)d_in[7];
    const float* d2W  = (const float*)d_in[8];
    const float* d2b  = (const float*)d_in[9];
    float* out = (float*)d_out;

    char* ws = (char*)d_ws;
    size_t off = 0;
    auto alloc = [&](size_t bytes) -> void* {
        void* p = ws + off;
        off += (bytes + 255) & ~(size_t)255;
        return p;
    };
    unsigned short* hb = (unsigned short*)alloc((size_t)NPAD * CH * 2);
    unsigned short* tb = (unsigned short*)alloc((size_t)NPAD * CH * 2);
    unsigned short* gb = (unsigned short*)alloc((size_t)NPAD * CH * 2);

    unsigned short* Wt = (unsigned short*)alloc((size_t)9 * 128 * 128 * 2);
    int* counts   = (int*)alloc((size_t)NN * 4);
    int* offs     = (int*)alloc((size_t)NN * 4);
    int* cursor   = (int*)alloc((size_t)NN * 4);
    int* srclist  = (int*)alloc((size_t)NE * 4);
    int* partial  = (int*)alloc(256 * 4);
    int* blockoff = (int*)alloc(256 * 4);
    float* pooled = (float*)alloc((size_t)NG * CH * 4);
    int* gcount   = (int*)alloc((size_t)NG * 4);

    hipMemsetAsync(counts, 0, (size_t)NN * 4, stream);
    hipMemsetAsync(cursor, 0, (size_t)NN * 4, stream);
    hipMemsetAsync(pooled, 0, (size_t)NG * CH * 4, stream);
    hipMemsetAsync(gcount, 0, (size_t)NG * 4, stream);

    // CSR build
    k_hist<<<(NE + 255) / 256, 256, 0, stream>>>(edst, counts, NE);
    k_gcount<<<(NN + 255) / 256, 256, 0, stream>>>(gid, gcount, NN);
    int nb = (NN + 255) / 256;  // 196
    k_scan1<<<nb, 256, 0, stream>>>(counts, partial, NN);
    k_scan2<<<1, 256, 0, stream>>>(partial, blockoff, nb);
    k_scan3<<<nb, 256, 0, stream>>>(counts, blockoff, offs, NN);
    k_fill<<<(NE + 255) / 256, 256, 0, stream>>>(esrc, edst, offs, cursor, srclist, NE);

    // prep: x -> bf16, conv weights -> bf16 transposed
    k_prep_x<<<(NN * CH / 4 + 255) / 256, 256, 0, stream>>>(x, hb, NN * CH / 4);
    k_prep_w<<<(9 * 128 * 128 + 255) / 256, 256, 0, stream>>>(convW, Wt, 9 * 128 * 128);

    int nblk = (NN + 127) / 128;  // 391
    for (int l = 0; l < 3; l++) {
        k_gather<<<NN / 16, 256, 0, stream>>>(hb, srclist, offs, counts, gb);
        k_dense<<<nblk, 256, 0, stream>>>(gb, Wt + (size_t)(l * 3 + 0) * 16384, convb + (l * 3 + 0) * CH, tb, nullptr, NN, 1, 0);
        k_dense<<<nblk, 256, 0, stream>>>(tb, Wt + (size_t)(l * 3 + 1) * 16384, convb + (l * 3 + 1) * CH, gb, nullptr, NN, 1, 0);
        if (l < 2) {
            k_dense<<<nblk, 256, 0, stream>>>(gb, Wt + (size_t)(l * 3 + 2) * 16384, convb + (l * 3 + 2) * CH, hb, nullptr, NN, 0, 0);
        } else {
            k_dense<<<nblk, 256, 0, stream>>>(gb, Wt + (size_t)(l * 3 + 2) * 16384, convb + (l * 3 + 2) * CH, pooled, gid, NN, 0, 1);
        }
    }
    k_head<<<NG, 128, 0, stream>>>(pooled, gcount, d1W, d1b, d2W, d2b, out);
}

// Round 4
// 321.654 us; speedup vs baseline: 2.1950x; 1.3490x over previous
//
#include <hip/hip_runtime.h>
#include <hip/hip_bf16.h>
#include <math.h>

#define NN 50000
#define NE 625000
#define NG 256
#define CH 128
#define NPAD 50048

typedef __attribute__((ext_vector_type(8))) short short8;
typedef __attribute__((ext_vector_type(4))) float floatx4;

__device__ __forceinline__ float bf2f_lo(unsigned u) {
    union { unsigned i; float f; } c; c.i = u << 16; return c.f;
}
__device__ __forceinline__ float bf2f_hi(unsigned u) {
    union { unsigned i; float f; } c; c.i = u & 0xffff0000u; return c.f;
}
__device__ __forceinline__ float bfu2f(unsigned short us) {
    union { unsigned i; float f; } c; c.i = ((unsigned)us) << 16; return c.f;
}
__device__ __forceinline__ unsigned short f2bfu(float f) {
    __hip_bfloat16 b = __float2bfloat16(f);
    union { __hip_bfloat16 b; unsigned short u; } c; c.b = b; return c.u;
}

// ---------------- CSR build ----------------

__global__ __launch_bounds__(256) void k_hist(const int* __restrict__ dst, int* __restrict__ counts, int n) {
    int e = blockIdx.x * 256 + threadIdx.x;
    if (e < n) atomicAdd(&counts[dst[e]], 1);
}

__global__ __launch_bounds__(256) void k_scan1(const int* __restrict__ counts, int* __restrict__ partial, int n) {
    __shared__ int s[256];
    int t = threadIdx.x;
    int i = blockIdx.x * 256 + t;
    s[t] = (i < n) ? counts[i] : 0;
    __syncthreads();
    for (int d = 128; d > 0; d >>= 1) {
        if (t < d) s[t] += s[t + d];
        __syncthreads();
    }
    if (t == 0) partial[blockIdx.x] = s[0];
}

__global__ __launch_bounds__(256) void k_scan2(const int* __restrict__ partial, int* __restrict__ blockoff, int nb) {
    __shared__ int s[256];
    int t = threadIdx.x;
    int v = (t < nb) ? partial[t] : 0;
    s[t] = v;
    __syncthreads();
    for (int d = 1; d < 256; d <<= 1) {
        int x = (t >= d) ? s[t - d] : 0;
        __syncthreads();
        s[t] += x;
        __syncthreads();
    }
    if (t < nb) blockoff[t] = s[t] - v;  // exclusive
}

__global__ __launch_bounds__(256) void k_scan3(const int* __restrict__ counts, const int* __restrict__ blockoff,
                                               int* __restrict__ offsets, int n) {
    __shared__ int s[256];
    int t = threadIdx.x;
    int i = blockIdx.x * 256 + t;
    int v = (i < n) ? counts[i] : 0;
    s[t] = v;
    __syncthreads();
    for (int d = 1; d < 256; d <<= 1) {
        int x = (t >= d) ? s[t - d] : 0;
        __syncthreads();
        s[t] += x;
        __syncthreads();
    }
    if (i < n) offsets[i] = s[t] - v + blockoff[blockIdx.x];
}

__global__ __launch_bounds__(256) void k_fill(const int* __restrict__ src, const int* __restrict__ dst,
                                              const int* __restrict__ offsets, int* __restrict__ cursor,
                                              int* __restrict__ srclist, int n) {
    int e = blockIdx.x * 256 + threadIdx.x;
    if (e < n) {
        int d = dst[e];
        int pos = atomicAdd(&cursor[d], 1);
        srclist[offsets[d] + pos] = src[e];
    }
}

// ---------------- prep: fp32 -> bf16 conversions ----------------

__global__ __launch_bounds__(256) void k_prep_x(const float* __restrict__ x, unsigned short* __restrict__ hb, int n4) {
    int i = blockIdx.x * 256 + threadIdx.x;
    if (i < n4) {
        float4 v = *(const float4*)&x[i * 4];
        ushort4 o;
        o.x = f2bfu(v.x); o.y = f2bfu(v.y); o.z = f2bfu(v.z); o.w = f2bfu(v.w);
        *(ushort4*)&hb[i * 4] = o;
    }
}

// transpose+convert 9 conv weight mats: Wt[mat][n][k] = W[mat][k][n]
__global__ __launch_bounds__(256) void k_prep_w(const float* __restrict__ W, unsigned short* __restrict__ Wt, int total) {
    int i = blockIdx.x * 256 + threadIdx.x;
    if (i < total) {
        int mat = i >> 14;
        int rem = i & 16383;
        int k = rem >> 7;
        int n = rem & 127;
        Wt[mat * 16384 + n * 128 + k] = f2bfu(W[i]);
    }
}

// ---------------- aggregation (bf16): out[n] = h[n] + sum_{e: dst=n} h[src(e)] ----------------

__global__ __launch_bounds__(256) void k_gather(const unsigned short* __restrict__ h, const int* __restrict__ srclist,
                                                const int* __restrict__ offsets, const int* __restrict__ counts,
                                                unsigned short* __restrict__ outb) {
    int t = threadIdx.x;
    int node = blockIdx.x * 16 + (t >> 4);
    int sub = t & 15;
    int off = offsets[node];
    int deg = counts[node];

    float acc[8];
    {
        uint4 v = *(const uint4*)&h[(size_t)node * CH + sub * 8];
        acc[0] = bf2f_lo(v.x); acc[1] = bf2f_hi(v.x);
        acc[2] = bf2f_lo(v.y); acc[3] = bf2f_hi(v.y);
        acc[4] = bf2f_lo(v.z); acc[5] = bf2f_hi(v.z);
        acc[6] = bf2f_lo(v.w); acc[7] = bf2f_hi(v.w);
    }
#define ACC8(v) \
    acc[0] += bf2f_lo(v.x); acc[1] += bf2f_hi(v.x); \
    acc[2] += bf2f_lo(v.y); acc[3] += bf2f_hi(v.y); \
    acc[4] += bf2f_lo(v.z); acc[5] += bf2f_hi(v.z); \
    acc[6] += bf2f_lo(v.w); acc[7] += bf2f_hi(v.w);
    int i = 0;
    for (; i + 3 < deg; i += 4) {
        int s0 = srclist[off + i];
        int s1 = srclist[off + i + 1];
        int s2 = srclist[off + i + 2];
        int s3 = srclist[off + i + 3];
        uint4 v0 = *(const uint4*)&h[(size_t)s0 * CH + sub * 8];
        uint4 v1 = *(const uint4*)&h[(size_t)s1 * CH + sub * 8];
        uint4 v2 = *(const uint4*)&h[(size_t)s2 * CH + sub * 8];
        uint4 v3 = *(const uint4*)&h[(size_t)s3 * CH + sub * 8];
        ACC8(v0) ACC8(v1) ACC8(v2) ACC8(v3)
    }
    for (; i < deg; i++) {
        int s0 = srclist[off + i];
        uint4 v0 = *(const uint4*)&h[(size_t)s0 * CH + sub * 8];
        ACC8(v0)
    }
#undef ACC8
    ushort4 o0, o1;
    o0.x = f2bfu(acc[0]); o0.y = f2bfu(acc[1]); o0.z = f2bfu(acc[2]); o0.w = f2bfu(acc[3]);
    o1.x = f2bfu(acc[4]); o1.y = f2bfu(acc[5]); o1.z = f2bfu(acc[6]); o1.w = f2bfu(acc[7]);
    *(ushort4*)&outb[(size_t)node * CH + sub * 8] = o0;
    *(ushort4*)&outb[(size_t)node * CH + sub * 8 + 4] = o1;
}

// ---------------- fused 3-stage GIN MLP layer (bf16 MFMA) ----------------
// Orientation: D = W^T (m=ch_out) x Act^T (n=node), K=ch_in=128.
// D-layout: lane holds n(node)=lane&15 fixed, m(ch)=q*4+reg -> 4 consecutive
// channels per lane => ds_write_b64 inter-stage repack; B-frag (fixed node,
// 8 consecutive ch) => ds_read_b128. XOR swizzle (chunk ^ node&15) keeps both
// patterns <=2-way on banks (free). A-frags (=Wt rows) reloaded per stage
// from L2-hot Wt. Two LDS buffers ping-pong; 1 barrier per stage.
// poolMode: run-length segment-sum over sorted gid within the block -> one
// atomicAdd per (thread, gid-run) (~1.3 atomics/thread).

__global__ __launch_bounds__(256, 2) void k_layer(const unsigned short* __restrict__ A,
                                                  const unsigned short* __restrict__ Wt3,
                                                  const float* __restrict__ bias3,
                                                  unsigned short* __restrict__ outb,
                                                  float* __restrict__ pooled,
                                                  const int* __restrict__ gid,
                                                  int nrows, int poolMode) {
    __shared__ unsigned short buf[2][128 * 128];  // 2 x 32 KB

    int t = threadIdx.x;
    int wave = t >> 6;
    int lane = t & 63;
    int q = lane >> 4;
    int ml = lane & 15;
    int waveM = (wave >> 1) * 64;  // ch_out half
    int waveN = (wave & 1) * 64;   // node half
    int rowBase = blockIdx.x * 128;

    // stage in: gather-output tile [128 nodes][128 ch] -> swizzled LDS
#pragma unroll
    for (int iter = 0; iter < 8; iter++) {
        int fid = t + iter * 256;
        int row = fid >> 4;
        int c = fid & 15;
        int r = rowBase + row;
        if (r >= nrows) r = nrows - 1;
        uint4 v = *(const uint4*)&A[(size_t)r * CH + c * 8];
        *(uint4*)&buf[0][row * 128 + ((c ^ (row & 15)) << 3)] = v;
    }
    __syncthreads();

    int rd = 0;
    for (int st = 0; st < 3; st++) {
        const unsigned short* Wm = Wt3 + st * 16384;
        const float* bs = bias3 + st * 128;

        floatx4 acc[4][4];
#pragma unroll
        for (int mt = 0; mt < 4; mt++)
#pragma unroll
            for (int nt = 0; nt < 4; nt++) acc[mt][nt] = (floatx4){0.f, 0.f, 0.f, 0.f};

#pragma unroll
        for (int s = 0; s < 4; s++) {
            short8 a[4], b[4];
#pragma unroll
            for (int mt = 0; mt < 4; mt++) {
                int m = waveM + mt * 16 + ml;
                a[mt] = *(const short8*)&Wm[m * 128 + s * 32 + q * 8];
            }
#pragma unroll
            for (int nt = 0; nt < 4; nt++) {
                int node = waveN + nt * 16 + ml;
                b[nt] = *(const short8*)&buf[rd][node * 128 + (((4 * s + q) ^ ml) << 3)];
            }
#pragma unroll
            for (int mt = 0; mt < 4; mt++)
#pragma unroll
                for (int nt = 0; nt < 4; nt++)
                    acc[mt][nt] = __builtin_amdgcn_mfma_f32_16x16x32_bf16(a[mt], b[nt], acc[mt][nt], 0, 0, 0);
        }

        int wr = rd ^ 1;
        int relu = (st < 2);
        int cw_base = (waveM >> 3);  // chunk base from ch_out half
#pragma unroll
        for (int mt = 0; mt < 4; mt++) {
            float4 bv = *(const float4*)&bs[waveM + mt * 16 + q * 4];
            float bva[4] = {bv.x, bv.y, bv.z, bv.w};
#pragma unroll
            for (int nt = 0; nt < 4; nt++) {
                int node = waveN + nt * 16 + ml;
                ushort4 o;
                float v0 = acc[mt][nt][0] + bva[0];
                float v1 = acc[mt][nt][1] + bva[1];
                float v2 = acc[mt][nt][2] + bva[2];
                float v3 = acc[mt][nt][3] + bva[3];
                if (relu) {
                    v0 = v0 > 0.f ? v0 : 0.f;
                    v1 = v1 > 0.f ? v1 : 0.f;
                    v2 = v2 > 0.f ? v2 : 0.f;
                    v3 = v3 > 0.f ? v3 : 0.f;
                }
                o.x = f2bfu(v0); o.y = f2bfu(v1); o.z = f2bfu(v2); o.w = f2bfu(v3);
                int cw = (cw_base + 2 * mt + (q >> 1)) ^ ml;
                *(ushort4*)&buf[wr][node * 128 + (cw << 3) + (q & 1) * 4] = o;
            }
        }
        __syncthreads();
        rd = wr;
    }

    if (!poolMode) {
        // coalesced copy-out: LDS (swizzled) -> global bf16 [node][ch]
#pragma unroll
        for (int iter = 0; iter < 8; iter++) {
            int fid = t + iter * 256;
            int row = fid >> 4;
            int c = fid & 15;
            int r = rowBase + row;
            if (r < nrows) {
                uint4 v = *(const uint4*)&buf[rd][row * 128 + ((c ^ (row & 15)) << 3)];
                *(uint4*)&outb[(size_t)r * CH + c * 8] = v;
            }
        }
    } else {
        // fused pool: run-length sum over sorted gid, one atomic per run
        int c = t & 127;
        int half = t >> 7;
        int n0 = half * 64;
        float runsum = 0.f;
        int curg = -1;
        for (int n = n0; n < n0 + 64; n++) {
            int r = rowBase + n;
            if (r >= nrows) break;
            int g = gid[r];
            unsigned short u = buf[rd][n * 128 + ((((c >> 3) ^ (n & 15))) << 3) + (c & 7)];
            float v = bfu2f(u);
            if (g != curg) {
                if (curg >= 0) atomicAdd(&pooled[(size_t)curg * CH + c], runsum);
                curg = g;
                runsum = 0.f;
            }
            runsum += v;
        }
        if (curg >= 0) atomicAdd(&pooled[(size_t)curg * CH + c], runsum);
    }
}

// ---------------- head: relu((pooled/cnt)@W1+b1) @ W2 + b2 -> softmax ----------------

__device__ int lowerb(const int* a, int n, int key) {
    int lo = 0, hi = n;
    while (lo < hi) {
        int mid = (lo + hi) >> 1;
        if (a[mid] < key) lo = mid + 1;
        else hi = mid;
    }
    return lo;
}

__global__ __launch_bounds__(128) void k_head(const float* __restrict__ pooled, const int* __restrict__ gid,
                                              const float* __restrict__ W1, const float* __restrict__ b1,
                                              const float* __restrict__ W2, const float* __restrict__ b2,
                                              float* __restrict__ out) {
    __shared__ float p[CH];
    __shared__ float h1[CH];
    __shared__ float lg[10];
    __shared__ int bounds[2];
    int b = blockIdx.x;
    int c = threadIdx.x;
    if (c == 0) bounds[0] = lowerb(gid, NN, b);
    if (c == 1) bounds[1] = lowerb(gid, NN, b + 1);
    __syncthreads();
    float cnt = (float)(bounds[1] - bounds[0]);
    if (cnt < 1.f) cnt = 1.f;
    p[c] = pooled[b * CH + c] / cnt;
    __syncthreads();
    float acc = b1[c];
    for (int k = 0; k < CH; k++) acc += p[k] * W1[k * CH + c];
    h1[c] = acc > 0.f ? acc : 0.f;
    __syncthreads();
    if (c < 10) {
        float a = b2[c];
        for (int k = 0; k < CH; k++) a += h1[k] * W2[k * 10 + c];
        lg[c] = a;
    }
    __syncthreads();
    if (c == 0) {
        float m = lg[0];
        for (int o = 1; o < 10; o++) m = fmaxf(m, lg[o]);
        float e[10];
        float s = 0.f;
        for (int o = 0; o < 10; o++) {
            e[o] = expf(lg[o] - m);
            s += e[o];
        }
        for (int o = 0; o < 10; o++) out[b * 10 + o] = e[o] / s;
    }
}

// ---------------- launch ----------------

extern "C" void kernel_launch(void* const* d_in, const int* in_sizes, int n_in,
                              void* d_out, int out_size, void* d_ws, size_t ws_size,
                              hipStream_t stream) {
    const float* x    = (const float*)d_in[0];
    const int* esrc   = (const int*)d_in[1];
    const int* edst   = (const int*)d_in[2];
    const int* gid    = (const int*)d_in[3];
    const float* convW = (const float*)d_in[4];
    const float* convb = (const float*)d_in[5];
    const float* d1W  = (const float*)d_in[6];
    const float* d1b  = (const float*)d_in[7];
    const float* d2W  = (const float*)d_in[8];
    const float* d2b  = (const float*)d_in[9];
    float* out = (float*)d_out;

    char* ws = (char*)d_ws;
    size_t off = 0;
    auto alloc = [&](size_t bytes) -> void* {
        void* p = ws + off;
        off += (bytes + 255) & ~(size_t)255;
        return p;
    };
    unsigned short* hb = (unsigned short*)alloc((size_t)NPAD * CH * 2);
    unsigned short* gb = (unsigned short*)alloc((size_t)NPAD * CH * 2);

    unsigned short* Wt = (unsigned short*)alloc((size_t)9 * 128 * 128 * 2);
    int* counts   = (int*)alloc((size_t)NN * 4);
    int* offs     = (int*)alloc((size_t)NN * 4);
    int* cursor   = (int*)alloc((size_t)NN * 4);
    int* srclist  = (int*)alloc((size_t)NE * 4);
    int* partial  = (int*)alloc(256 * 4);
    int* blockoff = (int*)alloc(256 * 4);
    float* pooled = (float*)alloc((size_t)NG * CH * 4);

    hipMemsetAsync(counts, 0, (size_t)NN * 4, stream);
    hipMemsetAsync(cursor, 0, (size_t)NN * 4, stream);
    hipMemsetAsync(pooled, 0, (size_t)NG * CH * 4, stream);

    // CSR build
    k_hist<<<(NE + 255) / 256, 256, 0, stream>>>(edst, counts, NE);
    int nb = (NN + 255) / 256;  // 196
    k_scan1<<<nb, 256, 0, stream>>>(counts, partial, NN);
    k_scan2<<<1, 256, 0, stream>>>(partial, blockoff, nb);
    k_scan3<<<nb, 256, 0, stream>>>(counts, blockoff, offs, NN);
    k_fill<<<(NE + 255) / 256, 256, 0, stream>>>(esrc, edst, offs, cursor, srclist, NE);

    // prep: x -> bf16, conv weights -> bf16 transposed
    k_prep_x<<<(NN * CH / 4 + 255) / 256, 256, 0, stream>>>(x, hb, NN * CH / 4);
    k_prep_w<<<(9 * 128 * 128 + 255) / 256, 256, 0, stream>>>(convW, Wt, 9 * 128 * 128);

    int nblk = (NN + 127) / 128;  // 391
    for (int l = 0; l < 3; l++) {
        k_gather<<<NN / 16, 256, 0, stream>>>(hb, srclist, offs, counts, gb);
        k_layer<<<nblk, 256, 0, stream>>>(gb, Wt + (size_t)l * 3 * 16384, convb + l * 3 * CH,
                                          hb, pooled, gid, NN, (l == 2) ? 1 : 0);
    }
    k_head<<<NG, 128, 0, stream>>>(pooled, gid, d1W, d1b, d2W, d2b, out);
}